// Round 1
// baseline (704.272 us; speedup 1.0000x reference)
//
#include <hip/hip_runtime.h>

#define N_NODES_C  50000
#define N_EDGES_C  1600000
#define FEAT       128
#define NREL       8
#define NBUCKETS   (N_NODES_C * NREL)   // 400000

// ---------------- workspace layout (bytes) ----------------
// counts  u32[400000]        @ 0          (1,600,000)
// offsets u32[400000]        @ 1,600,000  (1,600,000)
// cursor  u32[400000]        @ 3,200,000  (1,600,000)
// bsum    u32[512]           @ 4,800,000  (2,048)
// boff    u32[512]           @ 4,802,048  (2,048)
// sorted  uint2[1.6M]        @ 4,804,608  (12,800,000)
// H       f32[50000*128]     @ 17,604,608 (25,600,000)
// total = 43,204,608 bytes
#define WS_COUNTS   0
#define WS_OFFSETS  1600000
#define WS_CURSOR   3200000
#define WS_BSUM     4800000
#define WS_BOFF     4802048
#define WS_SORTED   4804608
#define WS_H        17604608
#define WS_NEEDED   43204608

__global__ void k_zero(unsigned* p, int n) {
    int i = blockIdx.x * blockDim.x + threadIdx.x;
    if (i < n) p[i] = 0u;
}

__global__ void k_hist(const int* __restrict__ dst, const int* __restrict__ et,
                       unsigned* __restrict__ counts) {
    int e = blockIdx.x * blockDim.x + threadIdx.x;
    if (e < N_EDGES_C) atomicAdd(&counts[dst[e] * NREL + et[e]], 1u);
}

// block-wise reduce of 1024 counts -> bsum[block]
__global__ void k_scan_a(const unsigned* __restrict__ counts, unsigned* __restrict__ bsum) {
    __shared__ unsigned s[1024];
    int t = threadIdx.x;
    int i = blockIdx.x * 1024 + t;
    s[t] = (i < NBUCKETS) ? counts[i] : 0u;
    __syncthreads();
    for (int o = 512; o > 0; o >>= 1) {
        if (t < o) s[t] += s[t + o];
        __syncthreads();
    }
    if (t == 0) bsum[blockIdx.x] = s[0];
}

// exclusive scan of nb (<=512) block sums, single block of 512
__global__ void k_scan_b(const unsigned* __restrict__ bsum, unsigned* __restrict__ boff, int nb) {
    __shared__ unsigned s[512];
    int t = threadIdx.x;
    unsigned v = (t < nb) ? bsum[t] : 0u;
    s[t] = v;
    __syncthreads();
    for (int o = 1; o < 512; o <<= 1) {
        unsigned u = (t >= o) ? s[t - o] : 0u;
        __syncthreads();
        s[t] += u;
        __syncthreads();
    }
    if (t < nb) boff[t] = s[t] - v;   // inclusive -> exclusive
}

// per-block exclusive scan + block offset; writes offsets and cursor(=offsets)
__global__ void k_scan_c(const unsigned* __restrict__ counts, const unsigned* __restrict__ boff,
                         unsigned* __restrict__ offsets, unsigned* __restrict__ cursor) {
    __shared__ unsigned s[1024];
    int t = threadIdx.x;
    int i = blockIdx.x * 1024 + t;
    unsigned v = (i < NBUCKETS) ? counts[i] : 0u;
    s[t] = v;
    __syncthreads();
    for (int o = 1; o < 1024; o <<= 1) {
        unsigned u = (t >= o) ? s[t - o] : 0u;
        __syncthreads();
        s[t] += u;
        __syncthreads();
    }
    if (i < NBUCKETS) {
        unsigned off = boff[blockIdx.x] + s[t] - v;
        offsets[i] = off;
        cursor[i]  = off;
    }
}

__global__ void k_scatter(const int* __restrict__ src, const int* __restrict__ dst,
                          const int* __restrict__ et, const float* __restrict__ norm,
                          unsigned* __restrict__ cursor, uint2* __restrict__ sorted) {
    int e = blockIdx.x * blockDim.x + threadIdx.x;
    if (e < N_EDGES_C) {
        int key = dst[e] * NREL + et[e];
        unsigned p = atomicAdd(&cursor[key], 1u);
        sorted[p] = make_uint2((unsigned)src[e], __float_as_uint(norm[e]));
    }
}

// fp32 tiled GEMM: H[m][n] = sum_k h[m][k] * W[k][n]   (M=50000, K=N=128)
// block 256 = 4 waves, tile BM=64 x BN=128, BK=32
#define BM 64
#define BK 32
__global__ __launch_bounds__(256) void k_gemm(const float* __restrict__ h,
                                              const float* __restrict__ W,
                                              float* __restrict__ H) {
    __shared__ float hsT[BK][BM];     // [k][m]  8 KB
    __shared__ float sW[BK][FEAT];    // [k][n] 16 KB
    int t  = threadIdx.x;
    int tx = t & 31;      // col group: cols tx*4..tx*4+3
    int ty = t >> 5;      // row group: rows ty*8..ty*8+7
    int row0 = blockIdx.x * BM;

    float acc[8][4];
#pragma unroll
    for (int j = 0; j < 8; j++)
#pragma unroll
        for (int c = 0; c < 4; c++) acc[j][c] = 0.f;

    for (int k0 = 0; k0 < FEAT; k0 += BK) {
        // stage h tile transposed: 64 rows x 32 k = 512 float4 loads, 2 per thread
#pragma unroll
        for (int i = 0; i < 2; i++) {
            int idx = t + i * 256;          // 0..511
            int m   = idx >> 3;
            int kq  = idx & 7;
            int row = row0 + m;
            float4 v = make_float4(0.f, 0.f, 0.f, 0.f);
            if (row < N_NODES_C)
                v = *(const float4*)&h[(size_t)row * FEAT + k0 + kq * 4];
            hsT[kq * 4 + 0][m] = v.x;
            hsT[kq * 4 + 1][m] = v.y;
            hsT[kq * 4 + 2][m] = v.z;
            hsT[kq * 4 + 3][m] = v.w;
        }
        // stage W tile: 32 x 128 = 1024 float4, 4 per thread
#pragma unroll
        for (int i = 0; i < 4; i++) {
            int fidx = (t + i * 256) * 4;   // flat float index 0..4095
            int k = fidx >> 7;
            int n = fidx & 127;
            *(float4*)&sW[k][n] = *(const float4*)&W[(size_t)(k0 + k) * FEAT + n];
        }
        __syncthreads();

#pragma unroll
        for (int k = 0; k < BK; k++) {
            float4 b4 = *(float4*)&sW[k][tx * 4];
            float4 a0 = *(float4*)&hsT[k][ty * 8];
            float4 a1 = *(float4*)&hsT[k][ty * 8 + 4];
            float a[8] = {a0.x, a0.y, a0.z, a0.w, a1.x, a1.y, a1.z, a1.w};
#pragma unroll
            for (int j = 0; j < 8; j++) {
                acc[j][0] += a[j] * b4.x;
                acc[j][1] += a[j] * b4.y;
                acc[j][2] += a[j] * b4.z;
                acc[j][3] += a[j] * b4.w;
            }
        }
        __syncthreads();
    }

#pragma unroll
    for (int j = 0; j < 8; j++) {
        int row = row0 + ty * 8 + j;
        if (row < N_NODES_C) {
            float4 v = make_float4(acc[j][0], acc[j][1], acc[j][2], acc[j][3]);
            *(float4*)&H[(size_t)row * FEAT + tx * 4] = v;
        }
    }
}

// one wave per dst node; bucket key = d*8 + r; accumulate msgs in registers.
// r==0: plain store; r>0: read-modify-write; r==NREL-1: fold ReLU.
__global__ __launch_bounds__(256) void k_acc(const float* __restrict__ H,
                                             const uint2* __restrict__ sorted,
                                             const unsigned* __restrict__ offsets,
                                             const unsigned* __restrict__ cursor,
                                             const float* __restrict__ brel,
                                             float* __restrict__ out, int r) {
    int wid  = blockIdx.x * (blockDim.x >> 6) + (threadIdx.x >> 6);
    int lane = threadIdx.x & 63;
    if (wid >= N_NODES_C) return;

    int key = wid * NREL + r;
    unsigned start = offsets[key];
    unsigned end   = cursor[key];    // = offsets + count after scatter

    float2 acc = make_float2(0.f, 0.f);
    float  csum = 0.f;
    for (unsigned e = start; e < end; e++) {
        uint2 rec = sorted[e];
        float nv  = __uint_as_float(rec.y);
        float2 v  = *(const float2*)&H[(size_t)rec.x * FEAT + lane * 2];
        acc.x += nv * v.x;
        acc.y += nv * v.y;
        csum  += nv;
    }
    float2 bb = *(const float2*)&brel[lane * 2];
    acc.x += csum * bb.x;
    acc.y += csum * bb.y;

    float2* op = (float2*)&out[(size_t)wid * FEAT + lane * 2];
    if (r == 0) {
        *op = acc;
    } else {
        float2 prev = *op;
        float2 nv2 = make_float2(prev.x + acc.x, prev.y + acc.y);
        if (r == NREL - 1) {
            nv2.x = fmaxf(nv2.x, 0.f);
            nv2.y = fmaxf(nv2.y, 0.f);
        }
        *op = nv2;
    }
}

extern "C" void kernel_launch(void* const* d_in, const int* in_sizes, int n_in,
                              void* d_out, int out_size, void* d_ws, size_t ws_size,
                              hipStream_t stream) {
    const float* h    = (const float*)d_in[0];
    const int*   src  = (const int*)d_in[1];
    const int*   dst  = (const int*)d_in[2];
    const int*   et   = (const int*)d_in[3];
    const float* norm = (const float*)d_in[4];
    const float* W    = (const float*)d_in[5];
    const float* b    = (const float*)d_in[6];
    float*       out  = (float*)d_out;

    if (ws_size < (size_t)WS_NEEDED) return;  // loud failure rather than OOB writes

    char* ws = (char*)d_ws;
    unsigned* counts  = (unsigned*)(ws + WS_COUNTS);
    unsigned* offsets = (unsigned*)(ws + WS_OFFSETS);
    unsigned* cursor  = (unsigned*)(ws + WS_CURSOR);
    unsigned* bsum    = (unsigned*)(ws + WS_BSUM);
    unsigned* boff    = (unsigned*)(ws + WS_BOFF);
    uint2*    sorted  = (uint2*)(ws + WS_SORTED);
    float*    H       = (float*)(ws + WS_H);

    int nb = (NBUCKETS + 1023) / 1024;  // 391

    k_zero<<<(NBUCKETS + 255) / 256, 256, 0, stream>>>(counts, NBUCKETS);
    k_hist<<<(N_EDGES_C + 255) / 256, 256, 0, stream>>>(dst, et, counts);
    k_scan_a<<<nb, 1024, 0, stream>>>(counts, bsum);
    k_scan_b<<<1, 512, 0, stream>>>(bsum, boff, nb);
    k_scan_c<<<nb, 1024, 0, stream>>>(counts, boff, offsets, cursor);
    k_scatter<<<(N_EDGES_C + 255) / 256, 256, 0, stream>>>(src, dst, et, norm, cursor, sorted);

    int gemm_grid = (N_NODES_C + BM - 1) / BM;          // 782
    int acc_grid  = (N_NODES_C + 3) / 4;                // 12500 blocks * 4 waves
    for (int r = 0; r < NREL; r++) {
        k_gemm<<<gemm_grid, 256, 0, stream>>>(h, W + (size_t)r * FEAT * FEAT, H);
        k_acc<<<acc_grid, 256, 0, stream>>>(H, sorted, offsets, cursor,
                                            b + (size_t)r * FEAT, out, r);
    }
}

// Round 2
// 536.484 us; speedup vs baseline: 1.3128x; 1.3128x over previous
//
#include <hip/hip_runtime.h>

#define N_NODES_C   50000
#define N_EDGES_C   1600000
#define FEAT        128
#define NREL        8
#define NBUCKETS    (N_NODES_C * NREL)     // 400000
#define NCHUNKS     8
#define CHUNK_NODES (N_NODES_C / NCHUNKS)  // 6250
#define CHUNK_KEYS  (CHUNK_NODES * NREL)   // 50000
#define KTOT        (NREL * FEAT)          // 1024
#define NKSTEP      (KTOT / 32)            // 32

// ---------------- workspace layout (bytes) ----------------
#define WS_COUNTS   0          // u32[400000]           1,600,000
#define WS_OFFSETS  1600000    // u32[400000]           1,600,000
#define WS_RANK     3200000    // u16[1.6M]             3,200,000
#define WS_BSUM     6400000    // u32[512]                  2,048
#define WS_BOFF     6402048    // u32[512]                  2,048
#define WS_SORTED   6404096    // u32[1.6M]             6,400,000
#define WS_HB       12804096   // bf16[50000*128]      12,800,000
#define WS_WT       25604096   // bf16[128][1024]         262,144
#define WS_CSUM     25866240   // f32[400000]           1,600,000
#define WS_X        27466240   // bf16[6250][1024]     12,800,000
#define WS_NEEDED   40266240

typedef __attribute__((ext_vector_type(8))) short bf16x8;
typedef __attribute__((ext_vector_type(4))) float f32x4;

__device__ __forceinline__ unsigned short f2bf(float f) {
    unsigned u = __float_as_uint(f);
    return (unsigned short)((u + 0x7fffu + ((u >> 16) & 1u)) >> 16);  // RNE
}
__device__ __forceinline__ float bf2f(unsigned short b) {
    return __uint_as_float((unsigned)b << 16);
}

// fused: cast h->bf16 | zero counts | build Wcat^T bf16 [n][r*128+k]
__global__ void k_prep(const float* __restrict__ h, const float* __restrict__ W,
                       unsigned* __restrict__ counts,
                       unsigned short* __restrict__ hb, unsigned short* __restrict__ wt) {
    int b = blockIdx.x, t = threadIdx.x;
    if (b < 3125) {                       // h cast: 6.4M elems, 8/thread
        int i = (b * 256 + t) * 8;
        float4 v0 = *(const float4*)&h[i];
        float4 v1 = *(const float4*)&h[i + 4];
        uint4 o;
        o.x = (unsigned)f2bf(v0.x) | ((unsigned)f2bf(v0.y) << 16);
        o.y = (unsigned)f2bf(v0.z) | ((unsigned)f2bf(v0.w) << 16);
        o.z = (unsigned)f2bf(v1.x) | ((unsigned)f2bf(v1.y) << 16);
        o.w = (unsigned)f2bf(v1.z) | ((unsigned)f2bf(v1.w) << 16);
        *(uint4*)&hb[i] = o;
    } else if (b < 3125 + 1563) {         // zero counts
        int i = (b - 3125) * 256 + t;
        if (i < NBUCKETS) counts[i] = 0u;
    } else {                              // Wcat^T: wt[n*1024 + rk] = W[rk*128 + n]
        int i = (b - 4688) * 256 + t;     // 0..131071
        int n = i >> 10, rk = i & 1023;
        wt[i] = f2bf(W[rk * 128 + n]);
    }
}

// counts[key]++ ; rank[e] = old value  (scatter becomes atomic-free)
__global__ void k_hist(const int* __restrict__ dst, const int* __restrict__ et,
                       unsigned* __restrict__ counts, unsigned short* __restrict__ rank) {
    int e = blockIdx.x * 256 + threadIdx.x;
    if (e < N_EDGES_C)
        rank[e] = (unsigned short)atomicAdd(&counts[dst[e] * NREL + et[e]], 1u);
}

__global__ void k_scan_a(const unsigned* __restrict__ counts, unsigned* __restrict__ bsum) {
    __shared__ unsigned s[1024];
    int t = threadIdx.x;
    int i = blockIdx.x * 1024 + t;
    s[t] = (i < NBUCKETS) ? counts[i] : 0u;
    __syncthreads();
    for (int o = 512; o > 0; o >>= 1) {
        if (t < o) s[t] += s[t + o];
        __syncthreads();
    }
    if (t == 0) bsum[blockIdx.x] = s[0];
}

__global__ void k_scan_b(const unsigned* __restrict__ bsum, unsigned* __restrict__ boff, int nb) {
    __shared__ unsigned s[512];
    int t = threadIdx.x;
    unsigned v = (t < nb) ? bsum[t] : 0u;
    s[t] = v;
    __syncthreads();
    for (int o = 1; o < 512; o <<= 1) {
        unsigned u = (t >= o) ? s[t - o] : 0u;
        __syncthreads();
        s[t] += u;
        __syncthreads();
    }
    if (t < nb) boff[t] = s[t] - v;
}

__global__ void k_scan_c(const unsigned* __restrict__ counts, const unsigned* __restrict__ boff,
                         unsigned* __restrict__ offsets) {
    __shared__ unsigned s[1024];
    int t = threadIdx.x;
    int i = blockIdx.x * 1024 + t;
    unsigned v = (i < NBUCKETS) ? counts[i] : 0u;
    s[t] = v;
    __syncthreads();
    for (int o = 1; o < 1024; o <<= 1) {
        unsigned u = (t >= o) ? s[t - o] : 0u;
        __syncthreads();
        s[t] += u;
        __syncthreads();
    }
    if (i < NBUCKETS) offsets[i] = boff[blockIdx.x] + s[t] - v;
}

// atomic-free scatter of 4B records: (src<<16) | bf16(norm)
__global__ void k_scatter(const int* __restrict__ src, const int* __restrict__ dst,
                          const int* __restrict__ et, const float* __restrict__ norm,
                          const unsigned* __restrict__ offsets,
                          const unsigned short* __restrict__ rank,
                          unsigned* __restrict__ sorted) {
    int e = blockIdx.x * 256 + threadIdx.x;
    if (e < N_EDGES_C) {
        int key = dst[e] * NREL + et[e];
        unsigned pos = offsets[key] + rank[e];
        sorted[pos] = ((unsigned)src[e] << 16) | (unsigned)f2bf(norm[e]);
    }
}

// one wave per (node,rel) bucket: X[local,:] = bf16( sum norm*h_bf16[src,:] ), csum[key]=sum norm
__global__ __launch_bounds__(256) void k_agg(const unsigned* __restrict__ sorted,
                                             const unsigned* __restrict__ offsets,
                                             const unsigned* __restrict__ counts,
                                             const unsigned short* __restrict__ hb,
                                             unsigned* __restrict__ X,   // as u32 (2 bf16)
                                             float* __restrict__ csum, int keyBase) {
    int w = threadIdx.x >> 6, lane = threadIdx.x & 63;
    int lb = blockIdx.x * 4 + w;          // 0..CHUNK_KEYS-1
    if (lb >= CHUNK_KEYS) return;
    int key = keyBase + lb;
    unsigned st = offsets[key], cnt = counts[key];
    float a0 = 0.f, a1 = 0.f, cs = 0.f;
    for (unsigned i = 0; i < cnt; i++) {
        unsigned rec = sorted[st + i];
        float nv = bf2f((unsigned short)(rec & 0xffffu));
        unsigned row = rec >> 16;
        unsigned hv = *(const unsigned*)&hb[row * FEAT + lane * 2];
        a0 += nv * __uint_as_float(hv << 16);
        a1 += nv * __uint_as_float(hv & 0xffff0000u);
        cs += nv;
    }
    X[lb * 64 + lane] = (unsigned)f2bf(a0) | ((unsigned)f2bf(a1) << 16);
    if (lane == 0) csum[key] = cs;
}

// out[g,:] = relu( X[g,:] @ Wcat + sum_r csum[g,r]*b[r,:] )
// block: 256 thr = 4 waves, 64 rows x 128 cols, K=1024 (32 ksteps of 32)
// B staged in LDS double-buffer, XOR-swizzled (G4), MFMA 16x16x32 bf16
__global__ __launch_bounds__(256) void k_gemm(const unsigned short* __restrict__ X,
                                              const unsigned short* __restrict__ wt,
                                              const float* __restrict__ csum,
                                              const float* __restrict__ bias,
                                              float* __restrict__ out, int nodeBase) {
    __shared__ char Bl[16384];            // 2 x 8KB halves: [128 n][32 k] bf16, swizzled
    int t = threadIdx.x, w = t >> 6, lane = t & 63;
    int r0 = blockIdx.x * 64;

    f32x4 acc[8];
#pragma unroll
    for (int i = 0; i < 8; i++) acc[i] = (f32x4){0.f, 0.f, 0.f, 0.f};

    int lrow = r0 + w * 16 + (lane & 15);
    int lrowc = (lrow < CHUNK_NODES) ? lrow : (CHUNK_NODES - 1);
    const unsigned short* Arow = X + (size_t)lrowc * KTOT + (lane >> 4) * 8;

    // staging map: thread stages 16B chunks c = 2t, 2t+1; chunk c -> n=c>>2, kc=c&3
    int sn0 = (2 * t) >> 2, skc0 = (2 * t) & 3;
    int sn1 = (2 * t + 1) >> 2, skc1 = (2 * t + 1) & 3;
    int sl0 = ((sn0 * 64 + skc0 * 16) ^ ((sn0 & 7) << 4));
    int sl1 = ((sn1 * 64 + skc1 * 16) ^ ((sn1 & 7) << 4));
    const uint4* g0 = (const uint4*)&wt[sn0 * KTOT + skc0 * 8];
    const uint4* g1 = (const uint4*)&wt[sn1 * KTOT + skc1 * 8];

    // prologue: stage kstep 0 into half 0
    *(uint4*)(Bl + sl0) = g0[0];
    *(uint4*)(Bl + sl1) = g1[0];
    __syncthreads();

    int ln = lane & 15;
    int lbase = (lane >> 4) * 16;         // k-subgroup byte offset within row

    for (int ks = 0; ks < NKSTEP; ks++) {
        int half = (ks & 1) * 8192;
        uint4 p0, p1;
        if (ks + 1 < NKSTEP) {            // issue next B loads early (hide under MFMA)
            p0 = g0[(ks + 1) * 4];        // +32 k = +64B = 4 uint4
            p1 = g1[(ks + 1) * 4];
        }
        bf16x8 af = *(const bf16x8*)(Arow + ks * 32);
#pragma unroll
        for (int tl = 0; tl < 8; tl++) {
            int n = tl * 16 + ln;
            const bf16x8* bp = (const bf16x8*)(Bl + half + ((n * 64 + lbase) ^ ((n & 7) << 4)));
            acc[tl] = __builtin_amdgcn_mfma_f32_16x16x32_bf16(af, *bp, acc[tl], 0, 0, 0);
        }
        if (ks + 1 < NKSTEP) {
            int half2 = ((ks + 1) & 1) * 8192;
            *(uint4*)(Bl + half2 + sl0) = p0;
            *(uint4*)(Bl + half2 + sl1) = p1;
        }
        __syncthreads();
    }

    // epilogue: bias via csum + ReLU. D mapping: col=lane&15, row=(lane>>4)*4+reg
#pragma unroll
    for (int i = 0; i < 4; i++) {
        int rl = r0 + w * 16 + (lane >> 4) * 4 + i;
        if (rl >= CHUNK_NODES) continue;
        int g = nodeBase + rl;
        float4 c0 = *(const float4*)&csum[(size_t)g * 8];
        float4 c1 = *(const float4*)&csum[(size_t)g * 8 + 4];
        float cs[8] = {c0.x, c0.y, c0.z, c0.w, c1.x, c1.y, c1.z, c1.w};
#pragma unroll
        for (int tl = 0; tl < 8; tl++) {
            int col = tl * 16 + ln;
            float v = acc[tl][i];
#pragma unroll
            for (int r = 0; r < 8; r++) v += cs[r] * bias[r * FEAT + col];
            out[(size_t)g * FEAT + col] = fmaxf(v, 0.f);
        }
    }
}

extern "C" void kernel_launch(void* const* d_in, const int* in_sizes, int n_in,
                              void* d_out, int out_size, void* d_ws, size_t ws_size,
                              hipStream_t stream) {
    const float* h    = (const float*)d_in[0];
    const int*   src  = (const int*)d_in[1];
    const int*   dst  = (const int*)d_in[2];
    const int*   et   = (const int*)d_in[3];
    const float* norm = (const float*)d_in[4];
    const float* W    = (const float*)d_in[5];
    const float* b    = (const float*)d_in[6];
    float*       out  = (float*)d_out;

    if (ws_size < (size_t)WS_NEEDED) return;

    char* ws = (char*)d_ws;
    unsigned*       counts  = (unsigned*)(ws + WS_COUNTS);
    unsigned*       offsets = (unsigned*)(ws + WS_OFFSETS);
    unsigned short* rank    = (unsigned short*)(ws + WS_RANK);
    unsigned*       bsum    = (unsigned*)(ws + WS_BSUM);
    unsigned*       boff    = (unsigned*)(ws + WS_BOFF);
    unsigned*       sorted  = (unsigned*)(ws + WS_SORTED);
    unsigned short* hb      = (unsigned short*)(ws + WS_HB);
    unsigned short* wt      = (unsigned short*)(ws + WS_WT);
    float*          csum    = (float*)(ws + WS_CSUM);
    unsigned*       X       = (unsigned*)(ws + WS_X);

    int nb = (NBUCKETS + 1023) / 1024;    // 391

    k_prep<<<3125 + 1563 + 512, 256, 0, stream>>>(h, W, counts, hb, wt);
    k_hist<<<(N_EDGES_C + 255) / 256, 256, 0, stream>>>(dst, et, counts, rank);
    k_scan_a<<<nb, 1024, 0, stream>>>(counts, bsum);
    k_scan_b<<<1, 512, 0, stream>>>(bsum, boff, nb);
    k_scan_c<<<nb, 1024, 0, stream>>>(counts, boff, offsets);
    k_scatter<<<(N_EDGES_C + 255) / 256, 256, 0, stream>>>(src, dst, et, norm, offsets, rank, sorted);

    int agg_grid  = (CHUNK_KEYS + 3) / 4;               // 12500
    int gemm_grid = (CHUNK_NODES + 63) / 64;            // 98
    for (int c = 0; c < NCHUNKS; c++) {
        k_agg<<<agg_grid, 256, 0, stream>>>(sorted, offsets, counts, hb, X, csum,
                                            c * CHUNK_KEYS);
        k_gemm<<<gemm_grid, 256, 0, stream>>>((const unsigned short*)X, wt, csum, b, out,
                                              c * CHUNK_NODES);
    }
}